// Round 7
// baseline (590.843 us; speedup 1.0000x reference)
//
#include <hip/hip_runtime.h>

#define NN 50000
#define NG 100
#define NPG 500
#define NE 800000
#define EPG 8000
#define EMBD 128
#define NL 4
#define CS_BLOCKS 1000
#define CS_ROWS 50

typedef __attribute__((ext_vector_type(8))) short short8v;
typedef __attribute__((ext_vector_type(4))) float float4v;
typedef __attribute__((ext_vector_type(2))) float f2;

__device__ __forceinline__ unsigned short f2bf(float v) {
  unsigned u = __float_as_uint(v);
  u += 0x7FFFu + ((u >> 16) & 1u);
  return (unsigned short)(u >> 16);
}

__device__ __forceinline__ float fexp2(float x) {
#if __has_builtin(__builtin_amdgcn_exp2f)
  return __builtin_amdgcn_exp2f(x);
#else
  float r; asm("v_exp_f32 %0, %1" : "=v"(r) : "v"(x)); return r;
#endif
}
__device__ __forceinline__ float flog2(float x) {
#if __has_builtin(__builtin_amdgcn_logf)
  return __builtin_amdgcn_logf(x);
#else
  float r; asm("v_log_f32 %0, %1" : "=v"(r) : "v"(x)); return r;
#endif
}
__device__ __forceinline__ float frcp(float x) {
#if __has_builtin(__builtin_amdgcn_rcpf)
  return __builtin_amdgcn_rcpf(x);
#else
  float r; asm("v_rcp_f32 %0, %1" : "=v"(r) : "v"(x)); return r;
#endif
}

__device__ __forceinline__ f2 unpk(unsigned v) {
  f2 r;
  r.x = __uint_as_float(v << 16);
  r.y = __uint_as_float(v & 0xffff0000u);
  return r;
}

// ---------------- Wcat^T (bf16) prep, column-permuted layout ----------------
// oc<128: i-f (Wf rows 0..127); 128<=oc<256: i-s (Ws rows 0..127);
// oc>=256: j-interleaved t=oc-256, p=t>>2, r=t&3, c=2p+(r&1), r<2->Wf else Ws, rows 128..255
__global__ void prep_w(const float* __restrict__ Wf, const float* __restrict__ Ws,
                       unsigned short* __restrict__ whT) {
  int idx = blockIdx.x * 256 + threadIdx.x;   // 4*512*128 = 262144
  int k = idx & 127;
  int oc = (idx >> 7) & 511;
  int l = idx >> 16;
  const float* W;
  int row, c;
  if (oc < 128) { W = Wf; row = k; c = oc; }
  else if (oc < 256) { W = Ws; row = k; c = oc - 128; }
  else {
    int t = oc - 256;
    int p = t >> 2, r = t & 3;
    c = 2 * p + (r & 1);
    W = (r < 2) ? Wf : Ws;
    row = 128 + k;
  }
  whT[idx] = f2bf(W[(size_t)l * 32896 + (size_t)row * 128 + c]);
}

// ---------------- x0 = emb[z] ----------------
__global__ void gather_x(const float* __restrict__ emb, const int* __restrict__ z,
                         float* __restrict__ x, unsigned short* __restrict__ xh) {
  const int total = NN * 32;
  for (int idx = blockIdx.x * 256 + threadIdx.x; idx < total; idx += gridDim.x * 256) {
    int n = idx >> 5, c4 = (idx & 31) * 4;
    float4 v = *(const float4*)(emb + (size_t)z[n] * EMBD + c4);
    size_t base = (size_t)idx * 4;
    *(float4*)(x + base) = v;
    ushort4 h;
    h.x = f2bf(v.x); h.y = f2bf(v.y); h.z = f2bf(v.z); h.w = f2bf(v.w);
    *(ushort4*)(xh + base) = h;
  }
}

// ---------------- CSR build: one block per graph, all in LDS ----------------
__global__ __launch_bounds__(512) void csr_build(const int* __restrict__ ei,
                                                 const float* __restrict__ pos,
                                                 int* __restrict__ offs, int* __restrict__ deg,
                                                 uint2* __restrict__ csr) {
  __shared__ int hist[NPG];
  __shared__ int scan[512];
  const int g = blockIdx.x, t = threadIdx.x;
  const int nbase = g * NPG;
  const int e0 = g * EPG;
  for (int n = t; n < NPG; n += 512) hist[n] = 0;
  __syncthreads();
  for (int e = t; e < EPG; e += 512) atomicAdd(&hist[ei[NE + e0 + e] - nbase], 1);
  __syncthreads();
  int v = (t < NPG) ? hist[t] : 0;
  scan[t] = v;
  __syncthreads();
  for (int d = 1; d < 512; d <<= 1) {
    int a = (t >= d) ? scan[t - d] : 0;
    __syncthreads();
    scan[t] += a;
    __syncthreads();
  }
  if (t < NPG) {
    int off = scan[t] - v;
    offs[nbase + t] = e0 + off;
    deg[nbase + t] = v;
    hist[t] = off;
  }
  __syncthreads();
  for (int e = t; e < EPG; e += 512) {
    int j = ei[e0 + e];
    int i = ei[NE + e0 + e];
    float dx = pos[i * 3 + 0] - pos[j * 3 + 0];
    float dy = pos[i * 3 + 1] - pos[j * 3 + 1];
    float dz = pos[i * 3 + 2] - pos[j * 3 + 2];
    float dist = sqrtf(dx * dx + dy * dy + dz * dz);
    int p = atomicAdd(&hist[i - nbase], 1);
    csr[e0 + p] = make_uint2((unsigned)j, __float_as_uint(dist));
  }
}

// ---------------- P[n][512] = x(bf16) @ Wcat (MFMA 16x16x32 bf16) ----------------
#define BM 128
#define BN 128
__global__ __launch_bounds__(256, 2) void gemm_proj(const unsigned short* __restrict__ xh,
                                                    const unsigned short* __restrict__ whT,
                                                    unsigned short* __restrict__ P, int l) {
  __shared__ __align__(16) unsigned short smem[32768];  // 64 KB: sA | sB, then sC view
  unsigned short* sA = smem;           // 16384 shorts (swizzled granules)
  unsigned short* sB = smem + 16384;   // 16384 shorts
  const int tid = threadIdx.x;
  const int R0 = blockIdx.x * BM;
  const int C0 = blockIdx.y * BN;
  for (int gid = tid; gid < BM * 16; gid += 256) {
    int row = gid >> 4, gc = gid & 15;
    int grow = R0 + row;
    uint4 v = make_uint4(0u, 0u, 0u, 0u);
    if (grow < NN) v = *(const uint4*)(xh + (size_t)grow * 128 + gc * 8);
    int gs = (gc & 8) | ((gc ^ row) & 7);
    *(uint4*)((char*)sA + row * 256 + gs * 16) = v;
  }
  for (int gid = tid; gid < BN * 16; gid += 256) {
    int c = gid >> 4, gc = gid & 15;
    uint4 v = *(const uint4*)(whT + ((size_t)l * 512 + C0 + c) * 128 + gc * 8);
    int gs = (gc & 8) | ((gc ^ c) & 7);
    *(uint4*)((char*)sB + c * 256 + gs * 16) = v;
  }
  __syncthreads();
  const int w = tid >> 6, lane = tid & 63;
  const int lr = lane & 15, lk = lane >> 4;
  float4v acc[2][8];
#pragma unroll
  for (int i = 0; i < 2; i++)
#pragma unroll
    for (int j = 0; j < 8; j++) acc[i][j] = (float4v){0.f, 0.f, 0.f, 0.f};
#pragma unroll
  for (int kb = 0; kb < 4; kb++) {
    int g = kb * 4 + lk;
    short8v a[2], b[8];
#pragma unroll
    for (int rf = 0; rf < 2; rf++) {
      int row = w * 32 + rf * 16 + lr;
      int gs = (g & 8) | ((g ^ row) & 7);
      a[rf] = *(const short8v*)((const char*)sA + row * 256 + gs * 16);
    }
#pragma unroll
    for (int cf = 0; cf < 8; cf++) {
      int c = cf * 16 + lr;
      int gs = (g & 8) | ((g ^ c) & 7);
      b[cf] = *(const short8v*)((const char*)sB + c * 256 + gs * 16);
    }
#pragma unroll
    for (int rf = 0; rf < 2; rf++)
#pragma unroll
      for (int cf = 0; cf < 8; cf++)
        acc[rf][cf] = __builtin_amdgcn_mfma_f32_16x16x32_bf16(a[rf], b[cf], acc[rf][cf], 0, 0, 0);
  }
  // coalesced C-write: stage bf16 tile in LDS (stride 136 shorts), then 16B stores
  __syncthreads();
  unsigned short* sC = smem;  // 128*136 = 17408 shorts = 34816 B <= 64 KB
#pragma unroll
  for (int rf = 0; rf < 2; rf++) {
#pragma unroll
    for (int cf = 0; cf < 8; cf++) {
      int col = cf * 16 + lr;
#pragma unroll
      for (int j = 0; j < 4; j++) {
        int row = w * 32 + rf * 16 + lk * 4 + j;
        sC[row * 136 + col] = f2bf(acc[rf][cf][j]);
      }
    }
  }
  __syncthreads();
  for (int it = tid; it < BM * 16; it += 256) {
    int row = it >> 4, gc = it & 15;
    int grow = R0 + row;
    if (grow < NN) {
      uint4 v = *(const uint4*)(sC + row * 136 + gc * 8);
      *(uint4*)(P + (size_t)grow * 512 + C0 + gc * 8) = v;
    }
  }
}

// ---------------- edge gather: one wave per dst node, XCD-chunked swizzle ----------------
__global__ __launch_bounds__(256) void edge_gather(const unsigned short* __restrict__ P,
                                                   const uint2* __restrict__ csr,
                                                   const int* __restrict__ offs,
                                                   const int* __restrict__ deg,
                                                   const float* __restrict__ Wf,
                                                   const float* __restrict__ bf,
                                                   const float* __restrict__ Ws,
                                                   const float* __restrict__ bs,
                                                   float* __restrict__ agg, int l) {
  const float L = 1.4426950408889634f;   // log2(e)
  const float LN2 = 0.6931471805599453f;
  const int lane = threadIdx.x & 63;
  const int wid = __builtin_amdgcn_readfirstlane(threadIdx.x >> 6);
  // bijective XCD-chunked swizzle: nwg = 12500, q = 1562, r = 4
  const int bid = blockIdx.x;
  const int xcd = bid & 7, bidx = bid >> 3;
  const int wg = (xcd < 4) ? xcd * 1563 + bidx : 4 * 1563 + (xcd - 4) * 1562 + bidx;
  const int i = wg * 4 + wid;
  const int f0 = lane * 2;

  const unsigned* Piu = (const unsigned*)(P + (size_t)i * 512);
  unsigned pif = Piu[lane];       // i-f (cols 0..127)
  unsigned pis = Piu[64 + lane];  // i-s (cols 128..255)

  float2 wfd = *(const float2*)(Wf + (size_t)l * 32896 + 256 * 128 + f0);
  float2 wsd = *(const float2*)(Ws + (size_t)l * 32896 + 256 * 128 + f0);
  float2 bfv = *(const float2*)(bf + l * 128 + f0);
  float2 bsv = *(const float2*)(bs + l * 128 + f0);

  f2 bflv, bslv, wflv, wslv;
  {
    f2 pi_f = unpk(pif), pi_s = unpk(pis);
    bflv.x = (pi_f.x + bfv.x) * L; bflv.y = (pi_f.y + bfv.y) * L;
    bslv.x = (pi_s.x + bsv.x) * L; bslv.y = (pi_s.y + bsv.y) * L;
    wflv.x = wfd.x * L; wflv.y = wfd.y * L;
    wslv.x = wsd.x * L; wslv.y = wsd.y * L;
  }

  const int off = __builtin_amdgcn_readfirstlane(offs[i]);
  const int nd = __builtin_amdgcn_readfirstlane(deg[i]);
  const uint2* ep = csr + off;
  f2 acc = (f2){0.f, 0.f};

#define EDGE_BODY(DVU, V)                                          \
  {                                                                \
    float dv = __uint_as_float(DVU);                               \
    f2 pf = unpk((V).x) * L + (bflv + dv * wflv);                  \
    f2 ps = unpk((V).y) * L + (bslv + dv * wslv);                  \
    f2 a, b, r, lg;                                                \
    a.x = fexp2(-pf.x); a.y = fexp2(-pf.y);                        \
    b.x = fexp2(ps.x);  b.y = fexp2(ps.y);                         \
    r.x = frcp(a.x + 1.f); r.y = frcp(a.y + 1.f);                  \
    lg.x = flog2(b.x + 1.f); lg.y = flog2(b.y + 1.f);              \
    acc += r * lg;                                                 \
  }

  int k = 0;
  for (; k + 3 < nd; k += 4) {
    uint2 ed = ep[k + (lane & 3)];   // lanes 0..3 hold edges k..k+3
    unsigned j0 = __builtin_amdgcn_readlane(ed.x, 0);
    unsigned d0 = __builtin_amdgcn_readlane(ed.y, 0);
    unsigned j1 = __builtin_amdgcn_readlane(ed.x, 1);
    unsigned d1 = __builtin_amdgcn_readlane(ed.y, 1);
    unsigned j2 = __builtin_amdgcn_readlane(ed.x, 2);
    unsigned d2 = __builtin_amdgcn_readlane(ed.y, 2);
    unsigned j3 = __builtin_amdgcn_readlane(ed.x, 3);
    unsigned d3 = __builtin_amdgcn_readlane(ed.y, 3);
    uint2 v0 = ((const uint2*)(P + (size_t)j0 * 512))[64 + lane];
    uint2 v1 = ((const uint2*)(P + (size_t)j1 * 512))[64 + lane];
    uint2 v2 = ((const uint2*)(P + (size_t)j2 * 512))[64 + lane];
    uint2 v3 = ((const uint2*)(P + (size_t)j3 * 512))[64 + lane];
    EDGE_BODY(d0, v0)
    EDGE_BODY(d1, v1)
    EDGE_BODY(d2, v2)
    EDGE_BODY(d3, v3)
  }
  for (; k < nd; k++) {
    uint2 e0 = ep[k];
    unsigned j0 = __builtin_amdgcn_readfirstlane(e0.x);
    unsigned d0 = __builtin_amdgcn_readfirstlane(e0.y);
    uint2 v0 = ((const uint2*)(P + (size_t)j0 * 512))[64 + lane];
    EDGE_BODY(d0, v0)
  }
#undef EDGE_BODY

  acc.x *= LN2; acc.y *= LN2;
  *(f2*)(agg + (size_t)i * EMBD + f0) = acc;
}

// ---------------- col stats: 1000 blocks x 50 rows, float4 coalesced ----------------
__global__ __launch_bounds__(256) void col_stats(const float* __restrict__ agg,
                                                 const float* __restrict__ x,
                                                 float* __restrict__ partial) {
  const int b = blockIdx.x, tid = threadIdx.x;
  const int c4 = tid & 31;        // column group (4 floats)
  const int h = tid >> 5;         // 0..7 row-group
  const int r0 = b * CS_ROWS;
  float4 sa = {0, 0, 0, 0}, sa2 = {0, 0, 0, 0}, sx = {0, 0, 0, 0}, sx2 = {0, 0, 0, 0},
         sax = {0, 0, 0, 0};
  for (int rr = h; rr < CS_ROWS; rr += 8) {
    size_t idx = (size_t)(r0 + rr) * EMBD + c4 * 4;
    float4 a = *(const float4*)(agg + idx);
    float4 xv = *(const float4*)(x + idx);
    sa.x += a.x; sa.y += a.y; sa.z += a.z; sa.w += a.w;
    sa2.x += a.x * a.x; sa2.y += a.y * a.y; sa2.z += a.z * a.z; sa2.w += a.w * a.w;
    sx.x += xv.x; sx.y += xv.y; sx.z += xv.z; sx.w += xv.w;
    sx2.x += xv.x * xv.x; sx2.y += xv.y * xv.y; sx2.z += xv.z * xv.z; sx2.w += xv.w * xv.w;
    sax.x += a.x * xv.x; sax.y += a.y * xv.y; sax.z += a.z * xv.z; sax.w += a.w * xv.w;
  }
  __shared__ float4 sm[256];
  float* p = partial + (size_t)b * 640;
#define REDUCE_STAT(V, OUTOFF)                                              \
  sm[tid] = V;                                                              \
  __syncthreads();                                                          \
  if (h == 0) {                                                             \
    float4 s = sm[tid];                                                     \
    for (int g = 1; g < 8; g++) {                                           \
      float4 o = sm[g * 32 + tid];                                          \
      s.x += o.x; s.y += o.y; s.z += o.z; s.w += o.w;                       \
    }                                                                       \
    *(float4*)(p + (OUTOFF) + c4 * 4) = s;                                  \
  }                                                                         \
  __syncthreads();
  REDUCE_STAT(sa, 0)
  REDUCE_STAT(sa2, 128)
  REDUCE_STAT(sx, 256)
  REDUCE_STAT(sx2, 384)
  REDUCE_STAT(sax, 512)
#undef REDUCE_STAT
}

// ---------------- fold: partial[1000][640] -> BN coeffs, 8 blocks x 16 cols ----------------
__global__ __launch_bounds__(256) void bn_fold(const float* __restrict__ partial,
                                               const float* __restrict__ bn1g,
                                               const float* __restrict__ bn1b,
                                               const float* __restrict__ bn2g,
                                               const float* __restrict__ bn2b,
                                               float* __restrict__ abc, int l) {
  __shared__ float sm[5 * 256];
  const int t = threadIdx.x;
  const int ci = t & 15;
  const int col = blockIdx.x * 16 + ci;
  const int chunk = t >> 4;   // 16 chunks
  float s0 = 0, s1 = 0, s2 = 0, s3 = 0, s4 = 0;
  for (int b = chunk; b < CS_BLOCKS; b += 16) {
    const float* p = partial + (size_t)b * 640 + col;
    s0 += p[0]; s1 += p[128]; s2 += p[256]; s3 += p[384]; s4 += p[512];
  }
  sm[t] = s0; sm[256 + t] = s1; sm[512 + t] = s2; sm[768 + t] = s3; sm[1024 + t] = s4;
  __syncthreads();
  if (t < 16) {
    int c = blockIdx.x * 16 + t;
    float a0 = 0, a1 = 0, a2 = 0, a3 = 0, a4 = 0;
    for (int ch = 0; ch < 16; ch++) {
      int u = ch * 16 + t;
      a0 += sm[u]; a1 += sm[256 + u]; a2 += sm[512 + u]; a3 += sm[768 + u]; a4 += sm[1024 + u];
    }
    const double Ninv = 1.0 / (double)NN;
    double Ea = a0 * Ninv, Ea2 = a1 * Ninv, Ex = a2 * Ninv, Ex2 = a3 * Ninv, Eax = a4 * Ninv;
    double var1 = Ea2 - Ea * Ea;
    double g1 = bn1g[l * 128 + c], b1 = bn1b[l * 128 + c];
    double g2 = bn2g[l * 128 + c], b2v = bn2b[l * 128 + c];
    double s1d = g1 / sqrt(var1 + 1e-5);
    double t1 = b1 - Ea * s1d;
    double mu_o = s1d * Ea + t1 + Ex;
    double Eo2 = s1d * s1d * Ea2 + 2.0 * s1d * t1 * Ea + t1 * t1 + 2.0 * (s1d * Eax + t1 * Ex) + Ex2;
    double var_o = Eo2 - mu_o * mu_o;
    double s2d = g2 / sqrt(var_o + 1e-5);
    double t2 = b2v - mu_o * s2d;
    abc[c] = (float)(s1d * s2d);
    abc[128 + c] = (float)s2d;
    abc[256 + c] = (float)(t1 * s2d + t2);
  }
}

// ---------------- x = relu(A*agg + B*x + C), also emit bf16 ----------------
__global__ void fuse_bn(const float* __restrict__ agg, float* __restrict__ x,
                        unsigned short* __restrict__ xh, const float* __restrict__ abc) {
  const int total = NN * 32;
  for (int idx = blockIdx.x * 256 + threadIdx.x; idx < total; idx += gridDim.x * 256) {
    int c4 = (idx & 31) * 4;
    size_t base = (size_t)idx * 4;
    float4 a = *(const float4*)(agg + base);
    float4 xv = *(const float4*)(x + base);
    float4 A = *(const float4*)(abc + c4);
    float4 B = *(const float4*)(abc + 128 + c4);
    float4 C = *(const float4*)(abc + 256 + c4);
    float4 o;
    o.x = fmaxf(fmaf(A.x, a.x, fmaf(B.x, xv.x, C.x)), 0.f);
    o.y = fmaxf(fmaf(A.y, a.y, fmaf(B.y, xv.y, C.y)), 0.f);
    o.z = fmaxf(fmaf(A.z, a.z, fmaf(B.z, xv.z, C.z)), 0.f);
    o.w = fmaxf(fmaf(A.w, a.w, fmaf(B.w, xv.w, C.w)), 0.f);
    *(float4*)(x + base) = o;
    ushort4 hh;
    hh.x = f2bf(o.x); hh.y = f2bf(o.y); hh.z = f2bf(o.z); hh.w = f2bf(o.w);
    *(ushort4*)(xh + base) = hh;
  }
}

// ---------------- global mean pool + final MLP (merged) ----------------
__global__ __launch_bounds__(512) void pool_mlp(const float* __restrict__ x,
                                                const float* __restrict__ W1,
                                                const float* __restrict__ b1,
                                                const float* __restrict__ W2,
                                                const float* __restrict__ b2,
                                                float* __restrict__ out) {
  __shared__ float red[512];
  __shared__ float gl[128];
  const int g = blockIdx.x, t = threadIdx.x;
  const int c = t & 127, q = t >> 7;
  const float* bx = x + (size_t)g * NPG * EMBD;
  float s = 0.f;
  for (int r = q; r < NPG; r += 4) s += bx[(size_t)r * EMBD + c];
  red[t] = s;
  __syncthreads();
  if (q == 0) gl[c] = (red[c] + red[128 + c] + red[256 + c] + red[384 + c]) * (1.f / NPG);
  __syncthreads();
  float acc = 0.f;
  for (int k = q * 32; k < q * 32 + 32; k++) acc = fmaf(gl[k], W1[k * EMBD + c], acc);
  red[t] = acc;
  __syncthreads();
  if (q == 0) {
    float h = fmaxf(red[c] + red[128 + c] + red[256 + c] + red[384 + c] + b1[c], 0.f);
    red[c] = h * W2[c];
  }
  __syncthreads();
  for (int sft = 64; sft > 0; sft >>= 1) {
    if (t < sft) red[t] += red[t + sft];
    __syncthreads();
  }
  if (t == 0) out[g] = red[0] + b2[0];
}

extern "C" void kernel_launch(void* const* d_in, const int* in_sizes, int n_in,
                              void* d_out, int out_size, void* d_ws, size_t ws_size,
                              hipStream_t stream) {
  const float* pos = (const float*)d_in[0];
  const float* emb = (const float*)d_in[1];
  const float* Wf = (const float*)d_in[2];
  const float* bf = (const float*)d_in[3];
  const float* Ws = (const float*)d_in[4];
  const float* bs = (const float*)d_in[5];
  const float* bn1g = (const float*)d_in[6];
  const float* bn1b = (const float*)d_in[7];
  const float* bn2g = (const float*)d_in[8];
  const float* bn2b = (const float*)d_in[9];
  const float* W1 = (const float*)d_in[10];
  const float* b1 = (const float*)d_in[11];
  const float* W2 = (const float*)d_in[12];
  const float* b2 = (const float*)d_in[13];
  const int* z = (const int*)d_in[14];
  const int* ei = (const int*)d_in[16];
  float* out = (float*)d_out;

  char* ws = (char*)d_ws;
  float* x = (float*)(ws + 0);                               // 25,600,000
  unsigned short* xh = (unsigned short*)(ws + 25600000);     // 12,800,000
  unsigned short* P = (unsigned short*)(ws + 38400000);      // 51,200,000
  float* agg = (float*)(ws + 89600000);                      // 25,600,000
  uint2* csr = (uint2*)(ws + 115200000);                     //  6,400,000
  int* deg = (int*)(ws + 121600000);                         //    200,000
  int* offs = (int*)(ws + 121800000);                        //    200,000
  unsigned short* whT = (unsigned short*)(ws + 122000000);   //    524,288
  float* partial = (float*)(ws + 122524288);                 //  2,560,000
  float* abc = (float*)(ws + 125084288);                     //      1,536

  prep_w<<<1024, 256, 0, stream>>>(Wf, Ws, whT);
  gather_x<<<2048, 256, 0, stream>>>(emb, z, x, xh);
  csr_build<<<NG, 512, 0, stream>>>(ei, pos, offs, deg, csr);
  for (int l = 0; l < NL; l++) {
    gemm_proj<<<dim3(391, 4), 256, 0, stream>>>(xh, whT, P, l);
    edge_gather<<<NN / 4, 256, 0, stream>>>(P, csr, offs, deg, Wf, bf, Ws, bs, agg, l);
    col_stats<<<CS_BLOCKS, 256, 0, stream>>>(agg, x, partial);
    bn_fold<<<8, 256, 0, stream>>>(partial, bn1g, bn1b, bn2g, bn2b, abc, l);
    fuse_bn<<<2048, 256, 0, stream>>>(agg, x, xh, abc);
  }
  pool_mlp<<<NG, 512, 0, stream>>>(x, W1, b1, W2, b2, out);
}

// Round 8
// 581.028 us; speedup vs baseline: 1.0169x; 1.0169x over previous
//
#include <hip/hip_runtime.h>

#define NN 50000
#define NG 100
#define NPG 500
#define NE 800000
#define EPG 8000
#define EMBD 128
#define NL 4
#define CS_BLOCKS 1000
#define CS_ROWS 50

typedef __attribute__((ext_vector_type(8))) short short8v;
typedef __attribute__((ext_vector_type(4))) float float4v;
typedef __attribute__((ext_vector_type(2))) float f2;

__device__ __forceinline__ unsigned short f2bf(float v) {
  unsigned u = __float_as_uint(v);
  u += 0x7FFFu + ((u >> 16) & 1u);
  return (unsigned short)(u >> 16);
}
__device__ __forceinline__ float bf2f(unsigned short h) {
  return __uint_as_float(((unsigned)h) << 16);
}

__device__ __forceinline__ float fexp2(float x) {
#if __has_builtin(__builtin_amdgcn_exp2f)
  return __builtin_amdgcn_exp2f(x);
#else
  float r; asm("v_exp_f32 %0, %1" : "=v"(r) : "v"(x)); return r;
#endif
}
__device__ __forceinline__ float flog2(float x) {
#if __has_builtin(__builtin_amdgcn_logf)
  return __builtin_amdgcn_logf(x);
#else
  float r; asm("v_log_f32 %0, %1" : "=v"(r) : "v"(x)); return r;
#endif
}
__device__ __forceinline__ float frcp(float x) {
#if __has_builtin(__builtin_amdgcn_rcpf)
  return __builtin_amdgcn_rcpf(x);
#else
  float r; asm("v_rcp_f32 %0, %1" : "=v"(r) : "v"(x)); return r;
#endif
}

__device__ __forceinline__ f2 unpk(unsigned v) {
  f2 r;
  r.x = __uint_as_float(v << 16);
  r.y = __uint_as_float(v & 0xffff0000u);
  return r;
}

// ---------------- Wcat^T (bf16) prep, column-permuted layout ----------------
// oc<128: i-f (Wf rows 0..127); 128<=oc<256: i-s (Ws rows 0..127);
// oc>=256: j-interleaved t=oc-256, p=t>>2, r=t&3, c=2p+(r&1), r<2->Wf else Ws, rows 128..255
__global__ void prep_w(const float* __restrict__ Wf, const float* __restrict__ Ws,
                       unsigned short* __restrict__ whT) {
  int idx = blockIdx.x * 256 + threadIdx.x;   // 4*512*128 = 262144
  int k = idx & 127;
  int oc = (idx >> 7) & 511;
  int l = idx >> 16;
  const float* W;
  int row, c;
  if (oc < 128) { W = Wf; row = k; c = oc; }
  else if (oc < 256) { W = Ws; row = k; c = oc - 128; }
  else {
    int t = oc - 256;
    int p = t >> 2, r = t & 3;
    c = 2 * p + (r & 1);
    W = (r < 2) ? Wf : Ws;
    row = 128 + k;
  }
  whT[idx] = f2bf(W[(size_t)l * 32896 + (size_t)row * 128 + c]);
}

// ---------------- xh0 = bf16(emb[z]) ----------------
__global__ void gather_x(const float* __restrict__ emb, const int* __restrict__ z,
                         unsigned short* __restrict__ xh) {
  const int total = NN * 32;
  for (int idx = blockIdx.x * 256 + threadIdx.x; idx < total; idx += gridDim.x * 256) {
    int n = idx >> 5, c4 = (idx & 31) * 4;
    float4 v = *(const float4*)(emb + (size_t)z[n] * EMBD + c4);
    ushort4 h;
    h.x = f2bf(v.x); h.y = f2bf(v.y); h.z = f2bf(v.z); h.w = f2bf(v.w);
    *(ushort4*)(xh + (size_t)idx * 4) = h;
  }
}

// ---------------- CSR build: one block per graph, all in LDS ----------------
__global__ __launch_bounds__(512) void csr_build(const int* __restrict__ ei,
                                                 const float* __restrict__ pos,
                                                 int* __restrict__ offs, int* __restrict__ deg,
                                                 uint2* __restrict__ csr) {
  __shared__ int hist[NPG];
  __shared__ int scan[512];
  const int g = blockIdx.x, t = threadIdx.x;
  const int nbase = g * NPG;
  const int e0 = g * EPG;
  for (int n = t; n < NPG; n += 512) hist[n] = 0;
  __syncthreads();
  for (int e = t; e < EPG; e += 512) atomicAdd(&hist[ei[NE + e0 + e] - nbase], 1);
  __syncthreads();
  int v = (t < NPG) ? hist[t] : 0;
  scan[t] = v;
  __syncthreads();
  for (int d = 1; d < 512; d <<= 1) {
    int a = (t >= d) ? scan[t - d] : 0;
    __syncthreads();
    scan[t] += a;
    __syncthreads();
  }
  if (t < NPG) {
    int off = scan[t] - v;
    offs[nbase + t] = e0 + off;
    deg[nbase + t] = v;
    hist[t] = off;
  }
  __syncthreads();
  for (int e = t; e < EPG; e += 512) {
    int j = ei[e0 + e];
    int i = ei[NE + e0 + e];
    float dx = pos[i * 3 + 0] - pos[j * 3 + 0];
    float dy = pos[i * 3 + 1] - pos[j * 3 + 1];
    float dz = pos[i * 3 + 2] - pos[j * 3 + 2];
    float dist = sqrtf(dx * dx + dy * dy + dz * dz);
    int p = atomicAdd(&hist[i - nbase], 1);
    csr[e0 + p] = make_uint2((unsigned)j, __float_as_uint(dist));
  }
}

// ---------------- P[n][512] = x(bf16) @ Wcat (MFMA 16x16x32 bf16) ----------------
#define BM 128
#define BN 128
__global__ __launch_bounds__(256, 2) void gemm_proj(const unsigned short* __restrict__ xh,
                                                    const unsigned short* __restrict__ whT,
                                                    unsigned short* __restrict__ P, int l) {
  __shared__ __align__(16) unsigned short smem[32768];  // 64 KB: sA | sB, then sC view
  unsigned short* sA = smem;
  unsigned short* sB = smem + 16384;
  const int tid = threadIdx.x;
  const int R0 = blockIdx.x * BM;
  const int C0 = blockIdx.y * BN;
  for (int gid = tid; gid < BM * 16; gid += 256) {
    int row = gid >> 4, gc = gid & 15;
    int grow = R0 + row;
    uint4 v = make_uint4(0u, 0u, 0u, 0u);
    if (grow < NN) v = *(const uint4*)(xh + (size_t)grow * 128 + gc * 8);
    int gs = (gc & 8) | ((gc ^ row) & 7);
    *(uint4*)((char*)sA + row * 256 + gs * 16) = v;
  }
  for (int gid = tid; gid < BN * 16; gid += 256) {
    int c = gid >> 4, gc = gid & 15;
    uint4 v = *(const uint4*)(whT + ((size_t)l * 512 + C0 + c) * 128 + gc * 8);
    int gs = (gc & 8) | ((gc ^ c) & 7);
    *(uint4*)((char*)sB + c * 256 + gs * 16) = v;
  }
  __syncthreads();
  const int w = tid >> 6, lane = tid & 63;
  const int lr = lane & 15, lk = lane >> 4;
  float4v acc[2][8];
#pragma unroll
  for (int i = 0; i < 2; i++)
#pragma unroll
    for (int j = 0; j < 8; j++) acc[i][j] = (float4v){0.f, 0.f, 0.f, 0.f};
#pragma unroll
  for (int kb = 0; kb < 4; kb++) {
    int g = kb * 4 + lk;
    short8v a[2], b[8];
#pragma unroll
    for (int rf = 0; rf < 2; rf++) {
      int row = w * 32 + rf * 16 + lr;
      int gs = (g & 8) | ((g ^ row) & 7);
      a[rf] = *(const short8v*)((const char*)sA + row * 256 + gs * 16);
    }
#pragma unroll
    for (int cf = 0; cf < 8; cf++) {
      int c = cf * 16 + lr;
      int gs = (g & 8) | ((g ^ c) & 7);
      b[cf] = *(const short8v*)((const char*)sB + c * 256 + gs * 16);
    }
#pragma unroll
    for (int rf = 0; rf < 2; rf++)
#pragma unroll
      for (int cf = 0; cf < 8; cf++)
        acc[rf][cf] = __builtin_amdgcn_mfma_f32_16x16x32_bf16(a[rf], b[cf], acc[rf][cf], 0, 0, 0);
  }
  __syncthreads();
  unsigned short* sC = smem;  // 128*136 shorts
#pragma unroll
  for (int rf = 0; rf < 2; rf++) {
#pragma unroll
    for (int cf = 0; cf < 8; cf++) {
      int col = cf * 16 + lr;
#pragma unroll
      for (int j = 0; j < 4; j++) {
        int row = w * 32 + rf * 16 + lk * 4 + j;
        sC[row * 136 + col] = f2bf(acc[rf][cf][j]);
      }
    }
  }
  __syncthreads();
  for (int it = tid; it < BM * 16; it += 256) {
    int row = it >> 4, gc = it & 15;
    int grow = R0 + row;
    if (grow < NN) {
      uint4 v = *(const uint4*)(sC + row * 136 + gc * 8);
      *(uint4*)(P + (size_t)grow * 512 + C0 + gc * 8) = v;
    }
  }
}

// ---------------- edge gather: one wave per dst node, 8-deep pipeline ----------------
__global__ __launch_bounds__(256) void edge_gather(const unsigned short* __restrict__ P,
                                                   const uint2* __restrict__ csr,
                                                   const int* __restrict__ offs,
                                                   const int* __restrict__ deg,
                                                   const float* __restrict__ Wf,
                                                   const float* __restrict__ bf,
                                                   const float* __restrict__ Ws,
                                                   const float* __restrict__ bs,
                                                   float* __restrict__ agg, int l) {
  const float L = 1.4426950408889634f;   // log2(e)
  const float LN2 = 0.6931471805599453f;
  const int lane = threadIdx.x & 63;
  const int wid = __builtin_amdgcn_readfirstlane(threadIdx.x >> 6);
  // bijective XCD-chunked swizzle: nwg = 12500, q = 1562, r = 4
  const int bid = blockIdx.x;
  const int xcd = bid & 7, bidx = bid >> 3;
  const int wg = (xcd < 4) ? xcd * 1563 + bidx : 4 * 1563 + (xcd - 4) * 1562 + bidx;
  const int i = wg * 4 + wid;
  const int f0 = lane * 2;

  const unsigned* Piu = (const unsigned*)(P + (size_t)i * 512);
  unsigned pif = Piu[lane];       // i-f (cols 0..127)
  unsigned pis = Piu[64 + lane];  // i-s (cols 128..255)

  float2 wfd = *(const float2*)(Wf + (size_t)l * 32896 + 256 * 128 + f0);
  float2 wsd = *(const float2*)(Ws + (size_t)l * 32896 + 256 * 128 + f0);
  float2 bfv = *(const float2*)(bf + l * 128 + f0);
  float2 bsv = *(const float2*)(bs + l * 128 + f0);

  f2 bflv, bslv, wflv, wslv;
  {
    f2 pi_f = unpk(pif), pi_s = unpk(pis);
    bflv.x = (pi_f.x + bfv.x) * L; bflv.y = (pi_f.y + bfv.y) * L;
    bslv.x = (pi_s.x + bsv.x) * L; bslv.y = (pi_s.y + bsv.y) * L;
    wflv.x = wfd.x * L; wflv.y = wfd.y * L;
    wslv.x = wsd.x * L; wslv.y = wsd.y * L;
  }

  const int off = __builtin_amdgcn_readfirstlane(offs[i]);
  const int nd = __builtin_amdgcn_readfirstlane(deg[i]);
  const uint2* ep = csr + off;
  f2 acc = (f2){0.f, 0.f};

#define EDGE_BODY(DVU, V)                                          \
  {                                                                \
    float dv = __uint_as_float(DVU);                               \
    f2 pf = unpk((V).x) * L + (bflv + dv * wflv);                  \
    f2 ps = unpk((V).y) * L + (bslv + dv * wslv);                  \
    f2 a, b, r, lg;                                                \
    a.x = fexp2(-pf.x); a.y = fexp2(-pf.y);                        \
    b.x = fexp2(ps.x);  b.y = fexp2(ps.y);                         \
    r.x = frcp(a.x + 1.f); r.y = frcp(a.y + 1.f);                  \
    lg.x = flog2(b.x + 1.f); lg.y = flog2(b.y + 1.f);              \
    acc += r * lg;                                                 \
  }

  for (int k = 0; k < nd; k += 8) {
    const int rem = nd - k;            // wave-uniform
    int le = lane & 7;
    if (le >= rem) le = rem - 1;       // clamp: lanes dup last valid edge
    uint2 ed = ep[k + le];
    unsigned js[8], ds[8];
#pragma unroll
    for (int e = 0; e < 8; e++) {
      js[e] = __builtin_amdgcn_readlane(ed.x, e);
      ds[e] = __builtin_amdgcn_readlane(ed.y, e);
    }
    uint2 v[8];
#pragma unroll
    for (int e = 0; e < 8; e++)
      v[e] = ((const uint2*)(P + (size_t)js[e] * 512))[64 + lane];
#pragma unroll
    for (int e = 0; e < 8; e++)
      if (e < rem) EDGE_BODY(ds[e], v[e])
  }
#undef EDGE_BODY

  acc.x *= LN2; acc.y *= LN2;
  *(f2*)(agg + (size_t)i * EMBD + f0) = acc;
}

// ---------------- col stats: agg f32 + x bf16 ----------------
__global__ __launch_bounds__(256) void col_stats(const float* __restrict__ agg,
                                                 const unsigned short* __restrict__ xh,
                                                 float* __restrict__ partial) {
  const int b = blockIdx.x, tid = threadIdx.x;
  const int c4 = tid & 31;
  const int h = tid >> 5;
  const int r0 = b * CS_ROWS;
  float4 sa = {0, 0, 0, 0}, sa2 = {0, 0, 0, 0}, sx = {0, 0, 0, 0}, sx2 = {0, 0, 0, 0},
         sax = {0, 0, 0, 0};
  for (int rr = h; rr < CS_ROWS; rr += 8) {
    size_t idx = (size_t)(r0 + rr) * EMBD + c4 * 4;
    float4 a = *(const float4*)(agg + idx);
    ushort4 hx = *(const ushort4*)(xh + idx);
    float x0 = bf2f(hx.x), x1 = bf2f(hx.y), x2 = bf2f(hx.z), x3 = bf2f(hx.w);
    sa.x += a.x; sa.y += a.y; sa.z += a.z; sa.w += a.w;
    sa2.x += a.x * a.x; sa2.y += a.y * a.y; sa2.z += a.z * a.z; sa2.w += a.w * a.w;
    sx.x += x0; sx.y += x1; sx.z += x2; sx.w += x3;
    sx2.x += x0 * x0; sx2.y += x1 * x1; sx2.z += x2 * x2; sx2.w += x3 * x3;
    sax.x += a.x * x0; sax.y += a.y * x1; sax.z += a.z * x2; sax.w += a.w * x3;
  }
  __shared__ float4 sm[256];
  float* p = partial + (size_t)b * 640;
#define REDUCE_STAT(V, OUTOFF)                                              \
  sm[tid] = V;                                                              \
  __syncthreads();                                                          \
  if (h == 0) {                                                             \
    float4 s = sm[tid];                                                     \
    for (int g = 1; g < 8; g++) {                                           \
      float4 o = sm[g * 32 + tid];                                          \
      s.x += o.x; s.y += o.y; s.z += o.z; s.w += o.w;                       \
    }                                                                       \
    *(float4*)(p + (OUTOFF) + c4 * 4) = s;                                  \
  }                                                                         \
  __syncthreads();
  REDUCE_STAT(sa, 0)
  REDUCE_STAT(sa2, 128)
  REDUCE_STAT(sx, 256)
  REDUCE_STAT(sx2, 384)
  REDUCE_STAT(sax, 512)
#undef REDUCE_STAT
}

// ---------------- fold: partial[1000][640] -> BN coeffs, 8 blocks x 16 cols ----------------
__global__ __launch_bounds__(256) void bn_fold(const float* __restrict__ partial,
                                               const float* __restrict__ bn1g,
                                               const float* __restrict__ bn1b,
                                               const float* __restrict__ bn2g,
                                               const float* __restrict__ bn2b,
                                               float* __restrict__ abc, int l) {
  __shared__ float sm[5 * 256];
  const int t = threadIdx.x;
  const int ci = t & 15;
  const int col = blockIdx.x * 16 + ci;
  const int chunk = t >> 4;
  float s0 = 0, s1 = 0, s2 = 0, s3 = 0, s4 = 0;
  for (int b = chunk; b < CS_BLOCKS; b += 16) {
    const float* p = partial + (size_t)b * 640 + col;
    s0 += p[0]; s1 += p[128]; s2 += p[256]; s3 += p[384]; s4 += p[512];
  }
  sm[t] = s0; sm[256 + t] = s1; sm[512 + t] = s2; sm[768 + t] = s3; sm[1024 + t] = s4;
  __syncthreads();
  if (t < 16) {
    int c = blockIdx.x * 16 + t;
    float a0 = 0, a1 = 0, a2 = 0, a3 = 0, a4 = 0;
    for (int ch = 0; ch < 16; ch++) {
      int u = ch * 16 + t;
      a0 += sm[u]; a1 += sm[256 + u]; a2 += sm[512 + u]; a3 += sm[768 + u]; a4 += sm[1024 + u];
    }
    const double Ninv = 1.0 / (double)NN;
    double Ea = a0 * Ninv, Ea2 = a1 * Ninv, Ex = a2 * Ninv, Ex2 = a3 * Ninv, Eax = a4 * Ninv;
    double var1 = Ea2 - Ea * Ea;
    double g1 = bn1g[l * 128 + c], b1 = bn1b[l * 128 + c];
    double g2 = bn2g[l * 128 + c], b2v = bn2b[l * 128 + c];
    double s1d = g1 / sqrt(var1 + 1e-5);
    double t1 = b1 - Ea * s1d;
    double mu_o = s1d * Ea + t1 + Ex;
    double Eo2 = s1d * s1d * Ea2 + 2.0 * s1d * t1 * Ea + t1 * t1 + 2.0 * (s1d * Eax + t1 * Ex) + Ex2;
    double var_o = Eo2 - mu_o * mu_o;
    double s2d = g2 / sqrt(var_o + 1e-5);
    double t2 = b2v - mu_o * s2d;
    abc[c] = (float)(s1d * s2d);
    abc[128 + c] = (float)s2d;
    abc[256 + c] = (float)(t1 * s2d + t2);
  }
}

// ---------------- xh = bf16(relu(A*agg + B*x + C)), in place ----------------
__global__ void fuse_bn(const float* __restrict__ agg, unsigned short* __restrict__ xh,
                        const float* __restrict__ abc) {
  const int total = NN * 32;
  for (int idx = blockIdx.x * 256 + threadIdx.x; idx < total; idx += gridDim.x * 256) {
    int c4 = (idx & 31) * 4;
    size_t base = (size_t)idx * 4;
    float4 a = *(const float4*)(agg + base);
    ushort4 hx = *(const ushort4*)(xh + base);
    float4 A = *(const float4*)(abc + c4);
    float4 B = *(const float4*)(abc + 128 + c4);
    float4 C = *(const float4*)(abc + 256 + c4);
    float4 o;
    o.x = fmaxf(fmaf(A.x, a.x, fmaf(B.x, bf2f(hx.x), C.x)), 0.f);
    o.y = fmaxf(fmaf(A.y, a.y, fmaf(B.y, bf2f(hx.y), C.y)), 0.f);
    o.z = fmaxf(fmaf(A.z, a.z, fmaf(B.z, bf2f(hx.z), C.z)), 0.f);
    o.w = fmaxf(fmaf(A.w, a.w, fmaf(B.w, bf2f(hx.w), C.w)), 0.f);
    ushort4 hh;
    hh.x = f2bf(o.x); hh.y = f2bf(o.y); hh.z = f2bf(o.z); hh.w = f2bf(o.w);
    *(ushort4*)(xh + base) = hh;
  }
}

// ---------------- global mean pool + final MLP (merged) ----------------
__global__ __launch_bounds__(512) void pool_mlp(const unsigned short* __restrict__ xh,
                                                const float* __restrict__ W1,
                                                const float* __restrict__ b1,
                                                const float* __restrict__ W2,
                                                const float* __restrict__ b2,
                                                float* __restrict__ out) {
  __shared__ float red[512];
  __shared__ float gl[128];
  const int g = blockIdx.x, t = threadIdx.x;
  const int c = t & 127, q = t >> 7;
  const unsigned short* bx = xh + (size_t)g * NPG * EMBD;
  float s = 0.f;
  for (int r = q; r < NPG; r += 4) s += bf2f(bx[(size_t)r * EMBD + c]);
  red[t] = s;
  __syncthreads();
  if (q == 0) gl[c] = (red[c] + red[128 + c] + red[256 + c] + red[384 + c]) * (1.f / NPG);
  __syncthreads();
  float acc = 0.f;
  for (int k = q * 32; k < q * 32 + 32; k++) acc = fmaf(gl[k], W1[k * EMBD + c], acc);
  red[t] = acc;
  __syncthreads();
  if (q == 0) {
    float h = fmaxf(red[c] + red[128 + c] + red[256 + c] + red[384 + c] + b1[c], 0.f);
    red[c] = h * W2[c];
  }
  __syncthreads();
  for (int sft = 64; sft > 0; sft >>= 1) {
    if (t < sft) red[t] += red[t + sft];
    __syncthreads();
  }
  if (t == 0) out[g] = red[0] + b2[0];
}

extern "C" void kernel_launch(void* const* d_in, const int* in_sizes, int n_in,
                              void* d_out, int out_size, void* d_ws, size_t ws_size,
                              hipStream_t stream) {
  const float* pos = (const float*)d_in[0];
  const float* emb = (const float*)d_in[1];
  const float* Wf = (const float*)d_in[2];
  const float* bf = (const float*)d_in[3];
  const float* Ws = (const float*)d_in[4];
  const float* bs = (const float*)d_in[5];
  const float* bn1g = (const float*)d_in[6];
  const float* bn1b = (const float*)d_in[7];
  const float* bn2g = (const float*)d_in[8];
  const float* bn2b = (const float*)d_in[9];
  const float* W1 = (const float*)d_in[10];
  const float* b1 = (const float*)d_in[11];
  const float* W2 = (const float*)d_in[12];
  const float* b2 = (const float*)d_in[13];
  const int* z = (const int*)d_in[14];
  const int* ei = (const int*)d_in[16];
  float* out = (float*)d_out;

  char* ws = (char*)d_ws;
  unsigned short* xh = (unsigned short*)(ws + 0);            // 12,800,000
  unsigned short* P = (unsigned short*)(ws + 12800000);      // 51,200,000
  float* agg = (float*)(ws + 64000000);                      // 25,600,000
  uint2* csr = (uint2*)(ws + 89600000);                      //  6,400,000
  int* deg = (int*)(ws + 96000000);                          //    200,000
  int* offs = (int*)(ws + 96200000);                         //    200,000
  unsigned short* whT = (unsigned short*)(ws + 96400000);    //    524,288
  float* partial = (float*)(ws + 96924288);                  //  2,560,000
  float* abc = (float*)(ws + 99484288);                      //      1,536

  prep_w<<<1024, 256, 0, stream>>>(Wf, Ws, whT);
  gather_x<<<2048, 256, 0, stream>>>(emb, z, xh);
  csr_build<<<NG, 512, 0, stream>>>(ei, pos, offs, deg, csr);
  for (int l = 0; l < NL; l++) {
    gemm_proj<<<dim3(391, 4), 256, 0, stream>>>(xh, whT, P, l);
    edge_gather<<<NN / 4, 256, 0, stream>>>(P, csr, offs, deg, Wf, bf, Ws, bs, agg, l);
    col_stats<<<CS_BLOCKS, 256, 0, stream>>>(agg, xh, partial);
    bn_fold<<<8, 256, 0, stream>>>(partial, bn1g, bn1b, bn2g, bn2b, abc, l);
    fuse_bn<<<2048, 256, 0, stream>>>(agg, xh, abc);
  }
  pool_mlp<<<NG, 512, 0, stream>>>(xh, W1, b1, W2, b2, out);
}

// Round 9
// 540.000 us; speedup vs baseline: 1.0942x; 1.0760x over previous
//
#include <hip/hip_runtime.h>

#define NN 50000
#define NG 100
#define NPG 500
#define NE 800000
#define EPG 8000
#define EMBD 128
#define NL 4
#define CS_BLOCKS 1000
#define CS_ROWS 50

typedef __attribute__((ext_vector_type(8))) short short8v;
typedef __attribute__((ext_vector_type(4))) float float4v;
typedef __attribute__((ext_vector_type(2))) float f2;

__device__ __forceinline__ unsigned short f2bf(float v) {
  unsigned u = __float_as_uint(v);
  u += 0x7FFFu + ((u >> 16) & 1u);
  return (unsigned short)(u >> 16);
}
__device__ __forceinline__ float bf2f(unsigned short h) {
  return __uint_as_float(((unsigned)h) << 16);
}

__device__ __forceinline__ float fexp2(float x) {
#if __has_builtin(__builtin_amdgcn_exp2f)
  return __builtin_amdgcn_exp2f(x);
#else
  float r; asm("v_exp_f32 %0, %1" : "=v"(r) : "v"(x)); return r;
#endif
}
__device__ __forceinline__ float flog2(float x) {
#if __has_builtin(__builtin_amdgcn_logf)
  return __builtin_amdgcn_logf(x);
#else
  float r; asm("v_log_f32 %0, %1" : "=v"(r) : "v"(x)); return r;
#endif
}
__device__ __forceinline__ float frcp(float x) {
#if __has_builtin(__builtin_amdgcn_rcpf)
  return __builtin_amdgcn_rcpf(x);
#else
  float r; asm("v_rcp_f32 %0, %1" : "=v"(r) : "v"(x)); return r;
#endif
}

__device__ __forceinline__ f2 unpk(unsigned v) {
  f2 r;
  r.x = __uint_as_float(v << 16);
  r.y = __uint_as_float(v & 0xffff0000u);
  return r;
}

// ---------------- Wcat^T (bf16) prep, column-permuted layout ----------------
// oc<128: i-f (Wf rows 0..127); 128<=oc<256: i-s (Ws rows 0..127);
// oc>=256: j-interleaved t=oc-256, p=t>>2, r=t&3, c=2p+(r&1), r<2->Wf else Ws, rows 128..255
__global__ void prep_w(const float* __restrict__ Wf, const float* __restrict__ Ws,
                       unsigned short* __restrict__ whT) {
  int idx = blockIdx.x * 256 + threadIdx.x;   // 4*512*128 = 262144
  int k = idx & 127;
  int oc = (idx >> 7) & 511;
  int l = idx >> 16;
  const float* W;
  int row, c;
  if (oc < 128) { W = Wf; row = k; c = oc; }
  else if (oc < 256) { W = Ws; row = k; c = oc - 128; }
  else {
    int t = oc - 256;
    int p = t >> 2, r = t & 3;
    c = 2 * p + (r & 1);
    W = (r < 2) ? Wf : Ws;
    row = 128 + k;
  }
  whT[idx] = f2bf(W[(size_t)l * 32896 + (size_t)row * 128 + c]);
}

// ---------------- xh0 = bf16(emb[z]) ----------------
__global__ void gather_x(const float* __restrict__ emb, const int* __restrict__ z,
                         unsigned short* __restrict__ xh) {
  const int total = NN * 32;
  for (int idx = blockIdx.x * 256 + threadIdx.x; idx < total; idx += gridDim.x * 256) {
    int n = idx >> 5, c4 = (idx & 31) * 4;
    float4 v = *(const float4*)(emb + (size_t)z[n] * EMBD + c4);
    ushort4 h;
    h.x = f2bf(v.x); h.y = f2bf(v.y); h.z = f2bf(v.z); h.w = f2bf(v.w);
    *(ushort4*)(xh + (size_t)idx * 4) = h;
  }
}

// ---------------- CSR build: one block per graph, all in LDS ----------------
__global__ __launch_bounds__(512) void csr_build(const int* __restrict__ ei,
                                                 const float* __restrict__ pos,
                                                 int* __restrict__ offs, int* __restrict__ deg,
                                                 uint2* __restrict__ csr) {
  __shared__ int hist[NPG];
  __shared__ int scan[512];
  const int g = blockIdx.x, t = threadIdx.x;
  const int nbase = g * NPG;
  const int e0 = g * EPG;
  for (int n = t; n < NPG; n += 512) hist[n] = 0;
  __syncthreads();
  for (int e = t; e < EPG; e += 512) atomicAdd(&hist[ei[NE + e0 + e] - nbase], 1);
  __syncthreads();
  int v = (t < NPG) ? hist[t] : 0;
  scan[t] = v;
  __syncthreads();
  for (int d = 1; d < 512; d <<= 1) {
    int a = (t >= d) ? scan[t - d] : 0;
    __syncthreads();
    scan[t] += a;
    __syncthreads();
  }
  if (t < NPG) {
    int off = scan[t] - v;
    offs[nbase + t] = e0 + off;
    deg[nbase + t] = v;
    hist[t] = off;
  }
  __syncthreads();
  for (int e = t; e < EPG; e += 512) {
    int j = ei[e0 + e];
    int i = ei[NE + e0 + e];
    float dx = pos[i * 3 + 0] - pos[j * 3 + 0];
    float dy = pos[i * 3 + 1] - pos[j * 3 + 1];
    float dz = pos[i * 3 + 2] - pos[j * 3 + 2];
    float dist = sqrtf(dx * dx + dy * dy + dz * dz);
    int p = atomicAdd(&hist[i - nbase], 1);
    csr[e0 + p] = make_uint2((unsigned)j, __float_as_uint(dist));
  }
}

// ---------------- P[n][512] = x(bf16) @ Wcat (MFMA 16x16x32 bf16) ----------------
// grid = dim3(4, 391): col-block fastest so 4 consecutive blocks share the A-tile
#define BM 128
#define BN 128
__global__ __launch_bounds__(256, 2) void gemm_proj(const unsigned short* __restrict__ xh,
                                                    const unsigned short* __restrict__ whT,
                                                    unsigned short* __restrict__ P, int l) {
  __shared__ __align__(16) unsigned short smem[32768];  // 64 KB: sA | sB, then sC view
  unsigned short* sA = smem;
  unsigned short* sB = smem + 16384;
  const int tid = threadIdx.x;
  const int R0 = blockIdx.y * BM;
  const int C0 = blockIdx.x * BN;
  for (int gid = tid; gid < BM * 16; gid += 256) {
    int row = gid >> 4, gc = gid & 15;
    int grow = R0 + row;
    uint4 v = make_uint4(0u, 0u, 0u, 0u);
    if (grow < NN) v = *(const uint4*)(xh + (size_t)grow * 128 + gc * 8);
    int gs = (gc & 8) | ((gc ^ row) & 7);
    *(uint4*)((char*)sA + row * 256 + gs * 16) = v;
  }
  for (int gid = tid; gid < BN * 16; gid += 256) {
    int c = gid >> 4, gc = gid & 15;
    uint4 v = *(const uint4*)(whT + ((size_t)l * 512 + C0 + c) * 128 + gc * 8);
    int gs = (gc & 8) | ((gc ^ c) & 7);
    *(uint4*)((char*)sB + c * 256 + gs * 16) = v;
  }
  __syncthreads();
  const int w = tid >> 6, lane = tid & 63;
  const int lr = lane & 15, lk = lane >> 4;
  float4v acc[2][8];
#pragma unroll
  for (int i = 0; i < 2; i++)
#pragma unroll
    for (int j = 0; j < 8; j++) acc[i][j] = (float4v){0.f, 0.f, 0.f, 0.f};
#pragma unroll
  for (int kb = 0; kb < 4; kb++) {
    int g = kb * 4 + lk;
    short8v a[2], b[8];
#pragma unroll
    for (int rf = 0; rf < 2; rf++) {
      int row = w * 32 + rf * 16 + lr;
      int gs = (g & 8) | ((g ^ row) & 7);
      a[rf] = *(const short8v*)((const char*)sA + row * 256 + gs * 16);
    }
#pragma unroll
    for (int cf = 0; cf < 8; cf++) {
      int c = cf * 16 + lr;
      int gs = (g & 8) | ((g ^ c) & 7);
      b[cf] = *(const short8v*)((const char*)sB + c * 256 + gs * 16);
    }
#pragma unroll
    for (int rf = 0; rf < 2; rf++)
#pragma unroll
      for (int cf = 0; cf < 8; cf++)
        acc[rf][cf] = __builtin_amdgcn_mfma_f32_16x16x32_bf16(a[rf], b[cf], acc[rf][cf], 0, 0, 0);
  }
  __syncthreads();
  unsigned short* sC = smem;  // 128*136 shorts
#pragma unroll
  for (int rf = 0; rf < 2; rf++) {
#pragma unroll
    for (int cf = 0; cf < 8; cf++) {
      int col = cf * 16 + lr;
#pragma unroll
      for (int j = 0; j < 4; j++) {
        int row = w * 32 + rf * 16 + lk * 4 + j;
        sC[row * 136 + col] = f2bf(acc[rf][cf][j]);
      }
    }
  }
  __syncthreads();
  for (int it = tid; it < BM * 16; it += 256) {
    int row = it >> 4, gc = it & 15;
    int grow = R0 + row;
    if (grow < NN) {
      uint4 v = *(const uint4*)(sC + row * 136 + gc * 8);
      *(uint4*)(P + (size_t)grow * 512 + C0 + gc * 8) = v;
    }
  }
}

// ---------------- edge gather: one wave per dst node, simple 4-unroll + XCD swizzle ----------------
__global__ __launch_bounds__(256) void edge_gather(const unsigned short* __restrict__ P,
                                                   const uint2* __restrict__ csr,
                                                   const int* __restrict__ offs,
                                                   const int* __restrict__ deg,
                                                   const float* __restrict__ Wf,
                                                   const float* __restrict__ bf,
                                                   const float* __restrict__ Ws,
                                                   const float* __restrict__ bs,
                                                   unsigned short* __restrict__ aggh, int l) {
  const float L = 1.4426950408889634f;   // log2(e)
  const float LN2 = 0.6931471805599453f;
  const int lane = threadIdx.x & 63;
  const int wid = __builtin_amdgcn_readfirstlane(threadIdx.x >> 6);
  // bijective XCD-chunked swizzle: nwg = 12500, q = 1562, r = 4
  const int bid = blockIdx.x;
  const int xcd = bid & 7, bidx = bid >> 3;
  const int wg = (xcd < 4) ? xcd * 1563 + bidx : 4 * 1563 + (xcd - 4) * 1562 + bidx;
  const int i = wg * 4 + wid;
  const int f0 = lane * 2;

  const unsigned* Piu = (const unsigned*)(P + (size_t)i * 512);
  unsigned pif = Piu[lane];       // i-f (cols 0..127)
  unsigned pis = Piu[64 + lane];  // i-s (cols 128..255)

  float2 wfd = *(const float2*)(Wf + (size_t)l * 32896 + 256 * 128 + f0);
  float2 wsd = *(const float2*)(Ws + (size_t)l * 32896 + 256 * 128 + f0);
  float2 bfv = *(const float2*)(bf + l * 128 + f0);
  float2 bsv = *(const float2*)(bs + l * 128 + f0);

  f2 bflv, bslv, wflv, wslv;
  {
    f2 pi_f = unpk(pif), pi_s = unpk(pis);
    bflv.x = (pi_f.x + bfv.x) * L; bflv.y = (pi_f.y + bfv.y) * L;
    bslv.x = (pi_s.x + bsv.x) * L; bslv.y = (pi_s.y + bsv.y) * L;
    wflv.x = wfd.x * L; wflv.y = wfd.y * L;
    wslv.x = wsd.x * L; wslv.y = wsd.y * L;
  }

  const int off = __builtin_amdgcn_readfirstlane(offs[i]);
  const int nd = __builtin_amdgcn_readfirstlane(deg[i]);
  const uint2* ep = csr + off;
  f2 acc = (f2){0.f, 0.f};

#define EDGE_BODY(DVU, V)                                          \
  {                                                                \
    float dv = __uint_as_float(DVU);                               \
    f2 pf = unpk((V).x) * L + (bflv + dv * wflv);                  \
    f2 ps = unpk((V).y) * L + (bslv + dv * wslv);                  \
    f2 a, b, r, lg;                                                \
    a.x = fexp2(-pf.x); a.y = fexp2(-pf.y);                        \
    b.x = fexp2(ps.x);  b.y = fexp2(ps.y);                         \
    r.x = frcp(a.x + 1.f); r.y = frcp(a.y + 1.f);                  \
    lg.x = flog2(b.x + 1.f); lg.y = flog2(b.y + 1.f);              \
    acc += r * lg;                                                 \
  }

  int k = 0;
  for (; k + 3 < nd; k += 4) {
    uint2 e0 = ep[k], e1 = ep[k + 1], e2 = ep[k + 2], e3 = ep[k + 3];
    unsigned j0 = __builtin_amdgcn_readfirstlane(e0.x);
    unsigned j1 = __builtin_amdgcn_readfirstlane(e1.x);
    unsigned j2 = __builtin_amdgcn_readfirstlane(e2.x);
    unsigned j3 = __builtin_amdgcn_readfirstlane(e3.x);
    unsigned d0 = __builtin_amdgcn_readfirstlane(e0.y);
    unsigned d1 = __builtin_amdgcn_readfirstlane(e1.y);
    unsigned d2 = __builtin_amdgcn_readfirstlane(e2.y);
    unsigned d3 = __builtin_amdgcn_readfirstlane(e3.y);
    uint2 v0 = ((const uint2*)(P + (size_t)j0 * 512))[64 + lane];
    uint2 v1 = ((const uint2*)(P + (size_t)j1 * 512))[64 + lane];
    uint2 v2 = ((const uint2*)(P + (size_t)j2 * 512))[64 + lane];
    uint2 v3 = ((const uint2*)(P + (size_t)j3 * 512))[64 + lane];
    EDGE_BODY(d0, v0)
    EDGE_BODY(d1, v1)
    EDGE_BODY(d2, v2)
    EDGE_BODY(d3, v3)
  }
  for (; k < nd; k++) {
    uint2 e0 = ep[k];
    unsigned j0 = __builtin_amdgcn_readfirstlane(e0.x);
    unsigned d0 = __builtin_amdgcn_readfirstlane(e0.y);
    uint2 v0 = ((const uint2*)(P + (size_t)j0 * 512))[64 + lane];
    EDGE_BODY(d0, v0)
  }
#undef EDGE_BODY

  acc.x *= LN2; acc.y *= LN2;
  unsigned packed = ((unsigned)f2bf(acc.y) << 16) | (unsigned)f2bf(acc.x);
  ((unsigned*)(aggh + (size_t)i * EMBD))[lane] = packed;
}

// ---------------- col stats: agg bf16 + x bf16 ----------------
__global__ __launch_bounds__(256) void col_stats(const unsigned short* __restrict__ aggh,
                                                 const unsigned short* __restrict__ xh,
                                                 float* __restrict__ partial) {
  const int b = blockIdx.x, tid = threadIdx.x;
  const int c4 = tid & 31;
  const int h = tid >> 5;
  const int r0 = b * CS_ROWS;
  float4 sa = {0, 0, 0, 0}, sa2 = {0, 0, 0, 0}, sx = {0, 0, 0, 0}, sx2 = {0, 0, 0, 0},
         sax = {0, 0, 0, 0};
  for (int rr = h; rr < CS_ROWS; rr += 8) {
    size_t idx = (size_t)(r0 + rr) * EMBD + c4 * 4;
    ushort4 ha = *(const ushort4*)(aggh + idx);
    ushort4 hx = *(const ushort4*)(xh + idx);
    float a0 = bf2f(ha.x), a1 = bf2f(ha.y), a2 = bf2f(ha.z), a3 = bf2f(ha.w);
    float x0 = bf2f(hx.x), x1 = bf2f(hx.y), x2 = bf2f(hx.z), x3 = bf2f(hx.w);
    sa.x += a0; sa.y += a1; sa.z += a2; sa.w += a3;
    sa2.x += a0 * a0; sa2.y += a1 * a1; sa2.z += a2 * a2; sa2.w += a3 * a3;
    sx.x += x0; sx.y += x1; sx.z += x2; sx.w += x3;
    sx2.x += x0 * x0; sx2.y += x1 * x1; sx2.z += x2 * x2; sx2.w += x3 * x3;
    sax.x += a0 * x0; sax.y += a1 * x1; sax.z += a2 * x2; sax.w += a3 * x3;
  }
  __shared__ float4 sm[256];
  float* p = partial + (size_t)b * 640;
#define REDUCE_STAT(V, OUTOFF)                                              \
  sm[tid] = V;                                                              \
  __syncthreads();                                                          \
  if (h == 0) {                                                             \
    float4 s = sm[tid];                                                     \
    for (int g = 1; g < 8; g++) {                                           \
      float4 o = sm[g * 32 + tid];                                          \
      s.x += o.x; s.y += o.y; s.z += o.z; s.w += o.w;                       \
    }                                                                       \
    *(float4*)(p + (OUTOFF) + c4 * 4) = s;                                  \
  }                                                                         \
  __syncthreads();
  REDUCE_STAT(sa, 0)
  REDUCE_STAT(sa2, 128)
  REDUCE_STAT(sx, 256)
  REDUCE_STAT(sx2, 384)
  REDUCE_STAT(sax, 512)
#undef REDUCE_STAT
}

// ---------------- fold: partial[1000][640] -> BN coeffs, 8 blocks x 16 cols ----------------
__global__ __launch_bounds__(256) void bn_fold(const float* __restrict__ partial,
                                               const float* __restrict__ bn1g,
                                               const float* __restrict__ bn1b,
                                               const float* __restrict__ bn2g,
                                               const float* __restrict__ bn2b,
                                               float* __restrict__ abc, int l) {
  __shared__ float sm[5 * 256];
  const int t = threadIdx.x;
  const int ci = t & 15;
  const int col = blockIdx.x * 16 + ci;
  const int chunk = t >> 4;
  float s0 = 0, s1 = 0, s2 = 0, s3 = 0, s4 = 0;
  for (int b = chunk; b < CS_BLOCKS; b += 16) {
    const float* p = partial + (size_t)b * 640 + col;
    s0 += p[0]; s1 += p[128]; s2 += p[256]; s3 += p[384]; s4 += p[512];
  }
  sm[t] = s0; sm[256 + t] = s1; sm[512 + t] = s2; sm[768 + t] = s3; sm[1024 + t] = s4;
  __syncthreads();
  if (t < 16) {
    int c = blockIdx.x * 16 + t;
    float a0 = 0, a1 = 0, a2 = 0, a3 = 0, a4 = 0;
    for (int ch = 0; ch < 16; ch++) {
      int u = ch * 16 + t;
      a0 += sm[u]; a1 += sm[256 + u]; a2 += sm[512 + u]; a3 += sm[768 + u]; a4 += sm[1024 + u];
    }
    const double Ninv = 1.0 / (double)NN;
    double Ea = a0 * Ninv, Ea2 = a1 * Ninv, Ex = a2 * Ninv, Ex2 = a3 * Ninv, Eax = a4 * Ninv;
    double var1 = Ea2 - Ea * Ea;
    double g1 = bn1g[l * 128 + c], b1 = bn1b[l * 128 + c];
    double g2 = bn2g[l * 128 + c], b2v = bn2b[l * 128 + c];
    double s1d = g1 / sqrt(var1 + 1e-5);
    double t1 = b1 - Ea * s1d;
    double mu_o = s1d * Ea + t1 + Ex;
    double Eo2 = s1d * s1d * Ea2 + 2.0 * s1d * t1 * Ea + t1 * t1 + 2.0 * (s1d * Eax + t1 * Ex) + Ex2;
    double var_o = Eo2 - mu_o * mu_o;
    double s2d = g2 / sqrt(var_o + 1e-5);
    double t2 = b2v - mu_o * s2d;
    abc[c] = (float)(s1d * s2d);
    abc[128 + c] = (float)s2d;
    abc[256 + c] = (float)(t1 * s2d + t2);
  }
}

// ---------------- xh = bf16(relu(A*agg + B*x + C)), in place ----------------
__global__ void fuse_bn(const unsigned short* __restrict__ aggh, unsigned short* __restrict__ xh,
                        const float* __restrict__ abc) {
  const int total = NN * 32;
  for (int idx = blockIdx.x * 256 + threadIdx.x; idx < total; idx += gridDim.x * 256) {
    int c4 = (idx & 31) * 4;
    size_t base = (size_t)idx * 4;
    ushort4 ha = *(const ushort4*)(aggh + base);
    ushort4 hx = *(const ushort4*)(xh + base);
    float4 A = *(const float4*)(abc + c4);
    float4 B = *(const float4*)(abc + 128 + c4);
    float4 C = *(const float4*)(abc + 256 + c4);
    float4 o;
    o.x = fmaxf(fmaf(A.x, bf2f(ha.x), fmaf(B.x, bf2f(hx.x), C.x)), 0.f);
    o.y = fmaxf(fmaf(A.y, bf2f(ha.y), fmaf(B.y, bf2f(hx.y), C.y)), 0.f);
    o.z = fmaxf(fmaf(A.z, bf2f(ha.z), fmaf(B.z, bf2f(hx.z), C.z)), 0.f);
    o.w = fmaxf(fmaf(A.w, bf2f(ha.w), fmaf(B.w, bf2f(hx.w), C.w)), 0.f);
    ushort4 hh;
    hh.x = f2bf(o.x); hh.y = f2bf(o.y); hh.z = f2bf(o.z); hh.w = f2bf(o.w);
    *(ushort4*)(xh + base) = hh;
  }
}

// ---------------- global mean pool + final MLP (merged) ----------------
__global__ __launch_bounds__(512) void pool_mlp(const unsigned short* __restrict__ xh,
                                                const float* __restrict__ W1,
                                                const float* __restrict__ b1,
                                                const float* __restrict__ W2,
                                                const float* __restrict__ b2,
                                                float* __restrict__ out) {
  __shared__ float red[512];
  __shared__ float gl[128];
  const int g = blockIdx.x, t = threadIdx.x;
  const int c = t & 127, q = t >> 7;
  const unsigned short* bx = xh + (size_t)g * NPG * EMBD;
  float s = 0.f;
  for (int r = q; r < NPG; r += 4) s += bf2f(bx[(size_t)r * EMBD + c]);
  red[t] = s;
  __syncthreads();
  if (q == 0) gl[c] = (red[c] + red[128 + c] + red[256 + c] + red[384 + c]) * (1.f / NPG);
  __syncthreads();
  float acc = 0.f;
  for (int k = q * 32; k < q * 32 + 32; k++) acc = fmaf(gl[k], W1[k * EMBD + c], acc);
  red[t] = acc;
  __syncthreads();
  if (q == 0) {
    float h = fmaxf(red[c] + red[128 + c] + red[256 + c] + red[384 + c] + b1[c], 0.f);
    red[c] = h * W2[c];
  }
  __syncthreads();
  for (int sft = 64; sft > 0; sft >>= 1) {
    if (t < sft) red[t] += red[t + sft];
    __syncthreads();
  }
  if (t == 0) out[g] = red[0] + b2[0];
}

extern "C" void kernel_launch(void* const* d_in, const int* in_sizes, int n_in,
                              void* d_out, int out_size, void* d_ws, size_t ws_size,
                              hipStream_t stream) {
  const float* pos = (const float*)d_in[0];
  const float* emb = (const float*)d_in[1];
  const float* Wf = (const float*)d_in[2];
  const float* bf = (const float*)d_in[3];
  const float* Ws = (const float*)d_in[4];
  const float* bs = (const float*)d_in[5];
  const float* bn1g = (const float*)d_in[6];
  const float* bn1b = (const float*)d_in[7];
  const float* bn2g = (const float*)d_in[8];
  const float* bn2b = (const float*)d_in[9];
  const float* W1 = (const float*)d_in[10];
  const float* b1 = (const float*)d_in[11];
  const float* W2 = (const float*)d_in[12];
  const float* b2 = (const float*)d_in[13];
  const int* z = (const int*)d_in[14];
  const int* ei = (const int*)d_in[16];
  float* out = (float*)d_out;

  char* ws = (char*)d_ws;
  unsigned short* xh = (unsigned short*)(ws + 0);            // 12,800,000
  unsigned short* P = (unsigned short*)(ws + 12800000);      // 51,200,000
  unsigned short* aggh = (unsigned short*)(ws + 64000000);   // 12,800,000
  uint2* csr = (uint2*)(ws + 76800000);                      //  6,400,000
  int* deg = (int*)(ws + 83200000);                          //    200,000
  int* offs = (int*)(ws + 83400000);                         //    200,000
  unsigned short* whT = (unsigned short*)(ws + 83600000);    //    524,288
  float* partial = (float*)(ws + 84124288);                  //  2,560,000
  float* abc = (float*)(ws + 86684288);                      //      1,536

  prep_w<<<1024, 256, 0, stream>>>(Wf, Ws, whT);
  gather_x<<<2048, 256, 0, stream>>>(emb, z, xh);
  csr_build<<<NG, 512, 0, stream>>>(ei, pos, offs, deg, csr);
  for (int l = 0; l < NL; l++) {
    gemm_proj<<<dim3(4, 391), 256, 0, stream>>>(xh, whT, P, l);
    edge_gather<<<NN / 4, 256, 0, stream>>>(P, csr, offs, deg, Wf, bf, Ws, bs, aggh, l);
    col_stats<<<CS_BLOCKS, 256, 0, stream>>>(aggh, xh, partial);
    bn_fold<<<8, 256, 0, stream>>>(partial, bn1g, bn1b, bn2g, bn2b, abc, l);
    fuse_bn<<<2048, 256, 0, stream>>>(aggh, xh, abc);
  }
  pool_mlp<<<NG, 512, 0, stream>>>(xh, W1, b1, W2, b2, out);
}